// Round 14
// baseline (87.704 us; speedup 1.0000x reference)
//
#include <hip/hip_runtime.h>
#include <hip/hip_bf16.h>
#include <stdint.h>

// BiLevelRoutingAttention (spiking LIF), T=4 B=2 L=8x32x32 C=256, fp32 I/O.
#define NT 4
#define NB 2
#define NW 32   // windows = 2*4*4
#define NS 256  // tokens/window = 4*8*8
#define NC 256
#define NH 8
#define ND 32
#define NK 4    // topk

typedef unsigned int u32;
typedef unsigned long long u64;
typedef unsigned short u16;
typedef __attribute__((ext_vector_type(8))) short bf16x8;
typedef __attribute__((ext_vector_type(4))) float f32x4;

// natural token index: tok = (t*NB+b)*8192 + Lt*1024 + Lh*32 + Lw
__device__ __forceinline__ int wofs(int w) {
  return (w >> 4) * 4096 + ((w >> 2) & 3) * 256 + (w & 3) * 8;
}
__device__ __forceinline__ int sofs(int s) {
  return ((s >> 6) << 10) + (((s >> 3) & 7) << 5) + (s & 7);
}
__device__ __forceinline__ size_t x_off(int t, int b, int w, int s, int c) {
  return ((size_t)((t * NB + b) * 8192 + wofs(w) + sofs(s))) * NC + c;
}

// fp32 -> bf16 round-to-nearest-even
__device__ __forceinline__ u32 f2bf(float f) {
  union { float f; u32 i; } u; u.f = f;
  return (u.i + 0x7FFFu + ((u.i >> 16) & 1u)) >> 16;
}

// async global(16B/lane) -> LDS (wave-uniform base + lane*16)
__device__ __forceinline__ void gload16(const u16* g, u16* l) {
  __builtin_amdgcn_global_load_lds(
      (const __attribute__((address_space(1))) void*)g,
      (__attribute__((address_space(3))) void*)l, 16, 0, 0);
}

// K1: w_qkv [256][768] fp32 -> bt [768][256] bf16 (transposed).
__global__ __launch_bounds__(256) void k_prepw(const float* __restrict__ w_qkv,
                                               u16* __restrict__ bt) {
  int n = blockIdx.x * 8 + (threadIdx.x >> 5);  // 0..767
  int kc = threadIdx.x & 31;                    // k-chunk of 8
  u16 vals[8];
#pragma unroll
  for (int j = 0; j < 8; ++j)
    vals[j] = (u16)f2bf(w_qkv[(size_t)(kc * 8 + j) * 768 + n]);
  *reinterpret_cast<uint4*>(&bt[(size_t)n * 256 + kc * 8]) =
      *reinterpret_cast<const uint4*>(vals);
}

// K2: MFMA GEMM, fused x-convert + region reduce.
// 128x256 tile (nt = q/k/v), BK=32 dbuf, 4 waves x 4x8 16x16x32 bf16 MFMA.
// A: reg-staged from fp32 x (cvt + swizzled ds_write). B: global_load_lds from bt
// (pre-swizzled source). nt==0 blocks also reduce region sums (atomicAdd).
// Spike bits (>=2.0) -> bitmasks via __ballot + per-window flags.
__global__ __launch_bounds__(256, 2) void k_gemm(const float* __restrict__ x,
                                                 const u16* __restrict__ bt,
                                                 const float* __restrict__ b_qkv,
                                                 u32* __restrict__ qb, u32* __restrict__ kb,
                                                 u32* __restrict__ vb,
                                                 u32* __restrict__ winflag,
                                                 float* __restrict__ region) {
  __shared__ __align__(16) u16 As[2][128 * 32];  // 16 KB
  __shared__ __align__(16) u16 Bs[2][256 * 32];  // 32 KB
  __shared__ float4 sums4[2][256];               // 8 KB
  __shared__ u32 wfl;

  const int tid = threadIdx.x;
  // XCD-chunked m-major: 3 consecutive v (q,k,v) share one m-tile (A L2 reuse).
  const int v = (blockIdx.x & 7) * 192 + (blockIdx.x >> 3);
  const int mt = v / 3, nt = v % 3;
  const int m0 = mt * 128, n0 = nt * 256;
  const int wave = tid >> 6, lane = tid & 63;
  const int wr = wave >> 1, wc = wave & 1;  // 2x2 waves of 64x128
  const bool doreg = (nt == 0);
  // region target decomposition of this m-tile (128 consecutive tokens)
  const int rb = (mt >> 6) & 1;
  const int v0 = (((mt >> 3) & 7) >> 2) * 16 + ((mt & 7) >> 1) * 4;

  if (tid == 0) wfl = 0;

  const f32x4 vz = {0.f, 0.f, 0.f, 0.f};
  f32x4 acc[4][8];
#pragma unroll
  for (int m = 0; m < 4; ++m)
#pragma unroll
    for (int n = 0; n < 8; ++n) acc[m][n] = vz;

  auto stage = [&](int buf, int ks) {
    const int k0 = ks * 32;
    // A: reg-staged fp32 -> bf16, swizzled ds_write.
    // thread: c4 = tid&7 (4 channels), rows = 32p + (tid>>3)
    const int c4 = tid & 7, rowid = tid >> 3;
    const int sl = c4 >> 1, half = c4 & 1;
    float4 sv = make_float4(0.f, 0.f, 0.f, 0.f);
#pragma unroll
    for (int p = 0; p < 4; ++p) {
      int row = p * 32 + rowid;
      float4 f = *reinterpret_cast<const float4*>(
          &x[(size_t)(m0 + row) * NC + k0 + c4 * 4]);
      if (doreg) { sv.x += f.x; sv.y += f.y; sv.z += f.z; sv.w += f.w; }
      uint2 bf;
      bf.x = f2bf(f.x) | (f2bf(f.y) << 16);
      bf.y = f2bf(f.z) | (f2bf(f.w) << 16);
      int phys = sl ^ ((row >> 1) & 3);
      *reinterpret_cast<uint2*>(&As[buf][row * 32 + phys * 8 + half * 4]) = bf;
    }
    if (doreg) sums4[ks & 1][tid] = sv;
    // B: 1024 16B-chunks (256 rows x 4 slots), 4 wave-rounds, gload_lds
#pragma unroll
    for (int p = 0; p < 4; ++p) {
      int cbase = (wave * 4 + p) * 64;
      int c = cbase + lane;
      int row = c >> 2, bsl = c & 3;
      int ssl = bsl ^ ((row >> 1) & 3);
      gload16(&bt[(size_t)(n0 + row) * 256 + k0 + ssl * 8], &Bs[buf][cbase * 8]);
    }
  };

  stage(0, 0);
  __syncthreads();
#pragma unroll
  for (int ks = 0; ks < 8; ++ks) {
    const int buf = ks & 1;
    // region reduce for step ks (sums4[ks&1] guarded by the preceding barrier;
    // this iteration's stage writes the OTHER sums4 buffer). channel c == tid.
    if (doreg && (tid >> 5) == ks) {
      int local = tid & 31, c4l = local >> 2, comp = local & 3;
      const float* sp = reinterpret_cast<const float*>(&sums4[ks & 1][0]);
#pragma unroll
      for (int ww = 0; ww < 4; ++ww) {
        float s = 0.f;
#pragma unroll
        for (int j = 0; j < 8; ++j) s += sp[((ww * 8 + j) * 8 + c4l) * 4 + comp];
        atomicAdd(&region[(size_t)(rb * NW + v0 + ww) * NC + tid],
                  s * (1.0f / 1024.0f));
      }
    }
    if (ks < 7) stage(buf ^ 1, ks + 1);
    bf16x8 afr[4], bfr[8];
#pragma unroll
    for (int m = 0; m < 4; ++m) {
      int r = wr * 64 + m * 16 + (lane & 15);
      int phys = (lane >> 4) ^ ((r >> 1) & 3);
      afr[m] = *reinterpret_cast<const bf16x8*>(&As[buf][r * 32 + phys * 8]);
    }
#pragma unroll
    for (int n = 0; n < 8; ++n) {
      int r = wc * 128 + n * 16 + (lane & 15);
      int phys = (lane >> 4) ^ ((r >> 1) & 3);
      bfr[n] = *reinterpret_cast<const bf16x8*>(&Bs[buf][r * 32 + phys * 8]);
    }
#pragma unroll
    for (int m = 0; m < 4; ++m)
#pragma unroll
      for (int n = 0; n < 8; ++n)
        acc[m][n] = __builtin_amdgcn_mfma_f32_16x16x32_bf16(afr[m], bfr[n], acc[m][n], 0, 0, 0);
    __syncthreads();
  }

  // epilogue: threshold via wave ballot (C/D: bit l -> row (l>>4)*4+r, col l&15)
  float bias[8];
#pragma unroll
  for (int n = 0; n < 8; ++n) bias[n] = b_qkv[n0 + wc * 128 + n * 16 + (lane & 15)];
  u32* dst = (nt == 0) ? qb : (nt == 1) ? kb : vb;
  const int g = lane >> 4;
  u32 wfl_loc = 0;
#pragma unroll
  for (int m = 0; m < 4; ++m)
#pragma unroll
    for (int r = 0; r < 4; ++r) {
      u32 words[4];
#pragma unroll
      for (int jp = 0; jp < 4; ++jp) {
        u64 b0 = __ballot(acc[m][2 * jp][r] + bias[2 * jp] >= 2.0f);
        u64 b1 = __ballot(acc[m][2 * jp + 1][r] + bias[2 * jp + 1] >= 2.0f);
        words[jp] = (u32)((b0 >> (g * 16)) & 0xFFFFu) |
                    ((u32)((b1 >> (g * 16)) & 0xFFFFu) << 16);
      }
      if ((lane & 15) < 4) {
        int jp = lane & 3;
        int row = wr * 64 + m * 16 + g * 4 + r;
        u32 wv = words[jp];
        dst[(size_t)(m0 + row) * NH + wc * 4 + jp] = wv;  // head = wc*4+jp
        if (wv) wfl_loc |= 1u << ((row & 31) >> 3);       // ww class
      }
    }
  if (wfl_loc) atomicOr(&wfl, wfl_loc);
  __syncthreads();
  if (tid == 0 && wfl) {
    u32 bit = 1u << nt;
    int t = mt >> 7;
    for (int ww = 0; ww < 4; ++ww)
      if (wfl & (1u << ww))
        atomicOr(&winflag[(t * NB + rb) * NW + v0 + ww], bit);
  }
}

// K3: scores + top-4 (ties -> lower index, matching jax.lax.top_k)
__global__ __launch_bounds__(256) void k_scores(const float* __restrict__ region,
                                                int* __restrict__ idx) {
  __shared__ float rs[NW][NC];  // 32 KB
  __shared__ float scval[NW];
  int blk = blockIdx.x;  // 64 = b*32 + w
  int b = blk >> 5, w = blk & 31;
  int tid = threadIdx.x;
  for (int i = tid; i < NW * NC; i += 256)
    rs[i >> 8][i & 255] = region[(size_t)b * NW * NC + i];
  __syncthreads();
  int v = tid >> 3, l8 = tid & 7;
  float sum = 0.f;
  const float* a = rs[w];
  const float* bb = rs[v];
#pragma unroll
  for (int j = 0; j < 32; ++j) sum += a[l8 * 32 + j] * bb[l8 * 32 + j];
  sum += __shfl_xor(sum, 1);
  sum += __shfl_xor(sum, 2);
  sum += __shfl_xor(sum, 4);
  if (l8 == 0) scval[v] = sum * 0.17677669529663687f;  // 32^-0.5
  __syncthreads();
  if (tid == 0) {
    float sc[NW];
#pragma unroll
    for (int j = 0; j < NW; ++j) sc[j] = scval[j];
    for (int kk = 0; kk < NK; ++kk) {
      float best = -__builtin_inff(); int bi = 0;
      for (int j = 0; j < NW; ++j)
        if (sc[j] > best) { best = sc[j]; bi = j; }
      idx[(b * NW + w) * NK + kk] = bi;
      sc[bi] = -__builtin_inff();
    }
  }
}

// K4: attention + proj + window reverse; s-chunked 4x; fast path via window flags.
__global__ __launch_bounds__(256) void k_attn(const u32* __restrict__ qb,
                                              const u32* __restrict__ kb,
                                              const u32* __restrict__ vb,
                                              const int* __restrict__ idx,
                                              const u32* __restrict__ winflag,
                                              const float* __restrict__ w_proj,
                                              const float* __restrict__ b_proj,
                                              float* __restrict__ out) {
  __shared__ u32 qs[64 * NH];
  __shared__ unsigned short kvc[NH * ND * ND];
  __shared__ u32 ksum[NH * ND];
  __shared__ float attnrow[NC];

  int blk = blockIdx.x;  // 1024 = wid*4 + sc
  int wid = blk >> 2, sc = blk & 3;
  int t = wid >> 6, b = (wid >> 5) & 1, w = wid & 31;
  int s0 = sc * 64;
  int tid = threadIdx.x;

  u32 fs = winflag[(t * NB + b) * NW + w];
  int wj[NK];
  u32 fk = 0, fv = 0;
#pragma unroll
  for (int j = 0; j < NK; ++j) {
    wj[j] = idx[(b * NW + w) * NK + j];
    u32 f = winflag[(t * NB + b) * NW + wj[j]];
    fk |= f & 2u; fv |= f & 4u;
  }
  bool skip = !(fs & 1u) || !fk || !fv;

  if (skip) {
    float bp = b_proj[tid];
    for (int s = s0; s < s0 + 64; ++s) out[x_off(t, b, w, s, tid)] = bp;
    return;
  }

  // ---- exact integer slow path (only if spikes exist) ----
  int tb = (t * NB + b) * 8192;
  size_t gb[NK];
#pragma unroll
  for (int j = 0; j < NK; ++j) gb[j] = (size_t)(tb + wofs(wj[j])) * NH;
  size_t qbase = (size_t)(tb + wofs(w)) * NH;
  for (int i = tid; i < 64 * NH; i += 256)
    qs[i] = qb[qbase + (size_t)sofs(s0 + (i >> 3)) * NH + (i & 7)];
  {
    int h = tid >> 5, d = tid & 31;
    u32 cnt = 0;
    for (int n = 0; n < NK * NS; ++n)
      cnt += (kb[gb[n >> 8] + (size_t)sofs(n & 255) * NH + h] >> d) & 1u;
    ksum[tid] = cnt;
  }
  for (int p = tid; p < NH * ND * ND; p += 256) {
    int h = p >> 10, d = (p >> 5) & 31, e = p & 31;
    u32 cnt = 0;
    for (int n = 0; n < NK * NS; ++n) {
      size_t a = gb[n >> 8] + (size_t)sofs(n & 255) * NH + h;
      cnt += ((kb[a] >> d) & (vb[a] >> e)) & 1u;
    }
    kvc[p] = (unsigned short)cnt;
  }
  __syncthreads();
  int h = tid >> 5, e = tid & 31;
  float bpv = b_proj[tid];
  for (int sl = 0; sl < 64; ++sl) {
    u32 qw = qs[sl * NH + h];
    float num = 0.f, den = 0.f;
    for (int d = 0; d < ND; ++d) {
      if ((qw >> d) & 1u) {
        den += (float)ksum[h * ND + d];
        num += (float)kvc[h * ND * ND + d * ND + e];
      }
    }
    attnrow[tid] = num / (den + 1e-6f);
    __syncthreads();
    float acc = bpv;
    for (int c = 0; c < NC; ++c) acc += attnrow[c] * w_proj[c * NC + tid];
    out[x_off(t, b, w, s0 + sl, tid)] = acc;
    __syncthreads();
  }
}

extern "C" void kernel_launch(void* const* d_in, const int* in_sizes, int n_in,
                              void* d_out, int out_size, void* d_ws, size_t ws_size,
                              hipStream_t stream) {
  const float* x      = (const float*)d_in[0];
  const float* w_qkv  = (const float*)d_in[1];
  const float* b_qkv  = (const float*)d_in[2];
  const float* w_proj = (const float*)d_in[3];
  const float* b_proj = (const float*)d_in[4];
  float* out = (float*)d_out;

  char* ws = (char*)d_ws;
  int* idx       = (int*)(ws + 0x200000);         // 1 KB
  u16* bt        = (u16*)(ws + 0x201000);         // 384 KB bf16 [768][256]
  u32* winflag   = (u32*)(ws + 0x270000);         // 1 KB (t,b,w): bit0 q, bit1 k, bit2 v
  float* region  = (float*)(ws + 0x271000);       // 64 KB [b][v][c]
  u32* qb        = (u32*)(ws + 0x300000);         // 2 MB each, natural token order
  u32* kb        = qb + (size_t)NT * NB * NW * NS * NH;
  u32* vb        = kb + (size_t)NT * NB * NW * NS * NH;

  (void)hipMemsetAsync(ws + 0x270000, 0, 0x11000, stream);  // winflag + region
  k_prepw<<<96, 256, 0, stream>>>(w_qkv, bt);
  k_gemm<<<1536, 256, 0, stream>>>(x, bt, b_qkv, qb, kb, vb, winflag, region);
  k_scores<<<NB * NW, 256, 0, stream>>>(region, idx);
  k_attn<<<NT * NB * NW * 4, 256, 0, stream>>>(qb, kb, vb, idx, winflag, w_proj, b_proj, out);
}

// Round 15
// 83.950 us; speedup vs baseline: 1.0447x; 1.0447x over previous
//
#include <hip/hip_runtime.h>
#include <hip/hip_bf16.h>
#include <stdint.h>

// BiLevelRoutingAttention (spiking LIF), T=4 B=2 L=8x32x32 C=256, fp32 I/O.
#define NT 4
#define NB 2
#define NW 32   // windows = 2*4*4
#define NS 256  // tokens/window = 4*8*8
#define NC 256
#define NH 8
#define ND 32
#define NK 4    // topk

typedef unsigned int u32;
typedef unsigned long long u64;
typedef unsigned short u16;
typedef __attribute__((ext_vector_type(8))) short bf16x8;
typedef __attribute__((ext_vector_type(4))) float f32x4;

// natural token index: tok = (t*NB+b)*8192 + Lt*1024 + Lh*32 + Lw
__device__ __forceinline__ int wofs(int w) {
  return (w >> 4) * 4096 + ((w >> 2) & 3) * 256 + (w & 3) * 8;
}
__device__ __forceinline__ int sofs(int s) {
  return ((s >> 6) << 10) + (((s >> 3) & 7) << 5) + (s & 7);
}
__device__ __forceinline__ size_t x_off(int t, int b, int w, int s, int c) {
  return ((size_t)((t * NB + b) * 8192 + wofs(w) + sofs(s))) * NC + c;
}

// fp32 -> bf16 round-to-nearest-even
__device__ __forceinline__ u32 f2bf(float f) {
  union { float f; u32 i; } u; u.f = f;
  return (u.i + 0x7FFFu + ((u.i >> 16) & 1u)) >> 16;
}

// async global(16B/lane) -> LDS (wave-uniform base + lane*16)
__device__ __forceinline__ void gload16(const u16* g, u16* l) {
  __builtin_amdgcn_global_load_lds(
      (const __attribute__((address_space(1))) void*)g,
      (__attribute__((address_space(3))) void*)l, 16, 0, 0);
}

// K1: prep. Blocks 0..511: x fp32 -> xw bf16 (natural order) + region atomics.
// Blocks 512..607: w_qkv -> bt (transposed bf16).
__global__ __launch_bounds__(256) void k_prep(const float* __restrict__ x,
                                              const float* __restrict__ w_qkv,
                                              u16* __restrict__ xw,
                                              u16* __restrict__ bt,
                                              float* __restrict__ region) {
  int blk = blockIdx.x, tid = threadIdx.x;
  if (blk >= 512) {
    int n = (blk - 512) * 8 + (tid >> 5);  // 0..767
    int kc = tid & 31;                     // k-chunk of 8
    u16 vals[8];
#pragma unroll
    for (int j = 0; j < 8; ++j)
      vals[j] = (u16)f2bf(w_qkv[(size_t)(kc * 8 + j) * 768 + n]);
    *reinterpret_cast<uint4*>(&bt[(size_t)n * 256 + kc * 8]) =
        *reinterpret_cast<const uint4*>(vals);
    return;
  }
  __shared__ float sums[4][4][NC];  // [ww][g][c] 16 KB
  int g = tid >> 6, c4 = tid & 63;
  size_t base = (size_t)blk * 128;  // 128 tokens/block
  float4 s[4];
#pragma unroll
  for (int ww = 0; ww < 4; ++ww) s[ww] = make_float4(0.f, 0.f, 0.f, 0.f);
#pragma unroll
  for (int p = 0; p < 32; ++p) {
    int row = p * 4 + g;
    float4 v = *reinterpret_cast<const float4*>(&x[(base + row) * NC + c4 * 4]);
    uint2 bf;
    bf.x = f2bf(v.x) | (f2bf(v.y) << 16);
    bf.y = f2bf(v.z) | (f2bf(v.w) << 16);
    *reinterpret_cast<uint2*>(&xw[(base + row) * NC + c4 * 4]) = bf;
    int ww = (p & 7) >> 1;  // = (row&31)>>3
    s[ww].x += v.x; s[ww].y += v.y; s[ww].z += v.z; s[ww].w += v.w;
  }
#pragma unroll
  for (int ww = 0; ww < 4; ++ww)
    *reinterpret_cast<float4*>(&sums[ww][g][c4 * 4]) = s[ww];
  __syncthreads();
  // blk = tb*64 + Lt*8 + hp ; wh = hp>>1, wt = Lt>>2
  int b = (blk >> 6) & 1;
  int wt = ((blk >> 3) & 7) >> 2, wh = (blk & 7) >> 1;
  int v0 = wt * 16 + wh * 4;
  int c = tid;
#pragma unroll
  for (int ww = 0; ww < 4; ++ww) {
    float tot = (sums[ww][0][c] + sums[ww][1][c] + sums[ww][2][c] + sums[ww][3][c]) *
                (1.0f / 1024.0f);
    atomicAdd(&region[((size_t)b * NW + v0 + ww) * NC + c], tot);
  }
}

// K2: scores + top-4 (ties -> lower index, matching jax.lax.top_k)
__global__ __launch_bounds__(256) void k_scores(const float* __restrict__ region,
                                                int* __restrict__ idx) {
  __shared__ float rs[NW][NC];  // 32 KB
  __shared__ float scval[NW];
  int blk = blockIdx.x;  // 64 = b*32 + w
  int b = blk >> 5, w = blk & 31;
  int tid = threadIdx.x;
  for (int i = tid; i < NW * NC; i += 256)
    rs[i >> 8][i & 255] = region[(size_t)b * NW * NC + i];
  __syncthreads();
  int v = tid >> 3, l8 = tid & 7;
  float sum = 0.f;
  const float* a = rs[w];
  const float* bb = rs[v];
#pragma unroll
  for (int j = 0; j < 32; ++j) sum += a[l8 * 32 + j] * bb[l8 * 32 + j];
  sum += __shfl_xor(sum, 1);
  sum += __shfl_xor(sum, 2);
  sum += __shfl_xor(sum, 4);
  if (l8 == 0) scval[v] = sum * 0.17677669529663687f;  // 32^-0.5
  __syncthreads();
  if (tid == 0) {
    float sc[NW];
#pragma unroll
    for (int j = 0; j < NW; ++j) sc[j] = scval[j];
    for (int kk = 0; kk < NK; ++kk) {
      float best = -__builtin_inff(); int bi = 0;
      for (int j = 0; j < NW; ++j)
        if (sc[j] > best) { best = sc[j]; bi = j; }
      idx[(b * NW + w) * NK + kk] = bi;
      sc[bi] = -__builtin_inff();
    }
  }
}

// K3: MFMA GEMM, 256x256 tile, 8 waves (2Mx4N), BK=64 double-buffered,
// counted-vmcnt pipeline (never drain to 0 in main loop), raw s_barrier.
// XOR-swizzled LDS (linear gload_lds dest + pre-swizzled source + swizzled read).
// qkv = xw @ w_qkv + b_qkv; spike bits (>=2.0) -> bitmasks via __ballot + winflags.
__global__ __launch_bounds__(512, 2) void k_gemm(const u16* __restrict__ xw,
                                                 const u16* __restrict__ bt,
                                                 const float* __restrict__ b_qkv,
                                                 u32* __restrict__ qb, u32* __restrict__ kb,
                                                 u32* __restrict__ vb,
                                                 u32* __restrict__ winflag) {
  __shared__ __align__(16) u16 As[2][256 * 64];  // 64 KB
  __shared__ __align__(16) u16 Bs[2][256 * 64];  // 64 KB
  __shared__ u32 wfl;

  const int tid = threadIdx.x;
  // XCD-chunked m-major: 3 consecutive v (q,k,v) share one m-tile (A L2 reuse).
  const int v = (blockIdx.x & 7) * 96 + (blockIdx.x >> 3);  // 768 blocks
  const int mt = v / 3, nt = v % 3;
  const int m0 = mt * 256, n0 = nt * 256;
  const int wave = tid >> 6, lane = tid & 63;
  const int wr = wave >> 2, wc = wave & 3;  // 2x4 waves of 128x64

  if (tid == 0) wfl = 0;

  const f32x4 vz = {0.f, 0.f, 0.f, 0.f};
  f32x4 acc[8][4];
#pragma unroll
  for (int m = 0; m < 8; ++m)
#pragma unroll
    for (int n = 0; n < 4; ++n) acc[m][n] = vz;

  // stage one K-tile (64 K): 2048 chunks A + 2048 chunks B, 4+4 gloads/thread
  auto stage = [&](int buf, int kt) {
    const int k0 = kt * 64;
#pragma unroll
    for (int i = 0; i < 4; ++i) {
      int c = i * 512 + tid;
      int row = c >> 3, p = c & 7;
      int sl = p ^ (row & 7);  // pre-swizzled source slot
      gload16(&xw[(size_t)(m0 + row) * 256 + k0 + sl * 8],
              &As[buf][(i * 512 + wave * 64) * 8]);
    }
#pragma unroll
    for (int i = 0; i < 4; ++i) {
      int c = i * 512 + tid;
      int row = c >> 3, p = c & 7;
      int sl = p ^ (row & 7);
      gload16(&bt[(size_t)(n0 + row) * 256 + k0 + sl * 8],
              &Bs[buf][(i * 512 + wave * 64) * 8]);
    }
  };

  stage(0, 0);
#pragma unroll
  for (int kt = 0; kt < 4; ++kt) {
    const int buf = kt & 1;
    if (kt < 3) {
      stage(buf ^ 1, kt + 1);  // issue next tile's 8 gloads (stay in flight)
      __builtin_amdgcn_sched_barrier(0);
      asm volatile("s_waitcnt vmcnt(8)" ::: "memory");  // tile kt complete
    } else {
      __builtin_amdgcn_sched_barrier(0);
      asm volatile("s_waitcnt vmcnt(0)" ::: "memory");
    }
    __builtin_amdgcn_s_barrier();  // all waves' tile-kt data visible
    __builtin_amdgcn_sched_barrier(0);
#pragma unroll
    for (int kk = 0; kk < 2; ++kk) {
      bf16x8 af[8], bfr[4];
#pragma unroll
      for (int m = 0; m < 8; ++m) {
        int r = wr * 128 + m * 16 + (lane & 15);
        int sl = kk * 4 + (lane >> 4);
        int phys = sl ^ (r & 7);
        af[m] = *reinterpret_cast<const bf16x8*>(&As[buf][r * 64 + phys * 8]);
      }
#pragma unroll
      for (int n = 0; n < 4; ++n) {
        int r = wc * 64 + n * 16 + (lane & 15);
        int sl = kk * 4 + (lane >> 4);
        int phys = sl ^ (r & 7);
        bfr[n] = *reinterpret_cast<const bf16x8*>(&Bs[buf][r * 64 + phys * 8]);
      }
#pragma unroll
      for (int m = 0; m < 8; ++m)
#pragma unroll
        for (int n = 0; n < 4; ++n)
          acc[m][n] = __builtin_amdgcn_mfma_f32_16x16x32_bf16(af[m], bfr[n], acc[m][n], 0, 0, 0);
    }
    __builtin_amdgcn_s_barrier();  // all waves done reading buf before restage
  }

  // epilogue: threshold via wave ballot (C/D: bit l -> row (l>>4)*4+r, col l&15)
  float bias[4];
#pragma unroll
  for (int n = 0; n < 4; ++n) bias[n] = b_qkv[n0 + wc * 64 + n * 16 + (lane & 15)];
  u32* dst = (nt == 0) ? qb : (nt == 1) ? kb : vb;
  const int g = lane >> 4;
  u32 wfl_loc = 0;
#pragma unroll
  for (int m = 0; m < 8; ++m)
#pragma unroll
    for (int r = 0; r < 4; ++r) {
      u32 words[2];
#pragma unroll
      for (int jp = 0; jp < 2; ++jp) {
        u64 b0 = __ballot(acc[m][2 * jp][r] + bias[2 * jp] >= 2.0f);
        u64 b1 = __ballot(acc[m][2 * jp + 1][r] + bias[2 * jp + 1] >= 2.0f);
        words[jp] = (u32)((b0 >> (g * 16)) & 0xFFFFu) |
                    ((u32)((b1 >> (g * 16)) & 0xFFFFu) << 16);
      }
      if ((lane & 15) < 2) {
        int jp = lane & 1;
        int row = wr * 128 + m * 16 + g * 4 + r;
        u32 wv = words[jp];
        dst[(size_t)(m0 + row) * NH + wc * 2 + jp] = wv;  // head = wc*2+jp
        if (wv) wfl_loc |= 1u << ((row & 31) >> 3);       // ww class
      }
    }
  if (wfl_loc) atomicOr(&wfl, wfl_loc);
  __syncthreads();
  if (tid == 0 && wfl) {
    int t = m0 >> 14, b = (m0 >> 13) & 1;
    int v0 = (((m0 >> 10) & 7) >> 2) * 16 + (((m0 >> 5) & 31) >> 3) * 4;
    u32 bit = 1u << nt;
    for (int ww = 0; ww < 4; ++ww)
      if (wfl & (1u << ww))
        atomicOr(&winflag[(t * NB + b) * NW + v0 + ww], bit);
  }
}

// K4: attention + proj + window reverse; s-chunked 4x; fast path via window flags.
__global__ __launch_bounds__(256) void k_attn(const u32* __restrict__ qb,
                                              const u32* __restrict__ kb,
                                              const u32* __restrict__ vb,
                                              const int* __restrict__ idx,
                                              const u32* __restrict__ winflag,
                                              const float* __restrict__ w_proj,
                                              const float* __restrict__ b_proj,
                                              float* __restrict__ out) {
  __shared__ u32 qs[64 * NH];
  __shared__ unsigned short kvc[NH * ND * ND];
  __shared__ u32 ksum[NH * ND];
  __shared__ float attnrow[NC];

  int blk = blockIdx.x;  // 1024 = wid*4 + sc
  int wid = blk >> 2, sc = blk & 3;
  int t = wid >> 6, b = (wid >> 5) & 1, w = wid & 31;
  int s0 = sc * 64;
  int tid = threadIdx.x;

  u32 fs = winflag[(t * NB + b) * NW + w];
  int wj[NK];
  u32 fk = 0, fv = 0;
#pragma unroll
  for (int j = 0; j < NK; ++j) {
    wj[j] = idx[(b * NW + w) * NK + j];
    u32 f = winflag[(t * NB + b) * NW + wj[j]];
    fk |= f & 2u; fv |= f & 4u;
  }
  bool skip = !(fs & 1u) || !fk || !fv;

  if (skip) {
    float bp = b_proj[tid];
    for (int s = s0; s < s0 + 64; ++s) out[x_off(t, b, w, s, tid)] = bp;
    return;
  }

  // ---- exact integer slow path (only if spikes exist) ----
  int tb = (t * NB + b) * 8192;
  size_t gb[NK];
#pragma unroll
  for (int j = 0; j < NK; ++j) gb[j] = (size_t)(tb + wofs(wj[j])) * NH;
  size_t qbase = (size_t)(tb + wofs(w)) * NH;
  for (int i = tid; i < 64 * NH; i += 256)
    qs[i] = qb[qbase + (size_t)sofs(s0 + (i >> 3)) * NH + (i & 7)];
  {
    int h = tid >> 5, d = tid & 31;
    u32 cnt = 0;
    for (int n = 0; n < NK * NS; ++n)
      cnt += (kb[gb[n >> 8] + (size_t)sofs(n & 255) * NH + h] >> d) & 1u;
    ksum[tid] = cnt;
  }
  for (int p = tid; p < NH * ND * ND; p += 256) {
    int h = p >> 10, d = (p >> 5) & 31, e = p & 31;
    u32 cnt = 0;
    for (int n = 0; n < NK * NS; ++n) {
      size_t a = gb[n >> 8] + (size_t)sofs(n & 255) * NH + h;
      cnt += ((kb[a] >> d) & (vb[a] >> e)) & 1u;
    }
    kvc[p] = (unsigned short)cnt;
  }
  __syncthreads();
  int h = tid >> 5, e = tid & 31;
  float bpv = b_proj[tid];
  for (int sl = 0; sl < 64; ++sl) {
    u32 qw = qs[sl * NH + h];
    float num = 0.f, den = 0.f;
    for (int d = 0; d < ND; ++d) {
      if ((qw >> d) & 1u) {
        den += (float)ksum[h * ND + d];
        num += (float)kvc[h * ND * ND + d * ND + e];
      }
    }
    attnrow[tid] = num / (den + 1e-6f);
    __syncthreads();
    float acc = bpv;
    for (int c = 0; c < NC; ++c) acc += attnrow[c] * w_proj[c * NC + tid];
    out[x_off(t, b, w, s0 + sl, tid)] = acc;
    __syncthreads();
  }
}

extern "C" void kernel_launch(void* const* d_in, const int* in_sizes, int n_in,
                              void* d_out, int out_size, void* d_ws, size_t ws_size,
                              hipStream_t stream) {
  const float* x      = (const float*)d_in[0];
  const float* w_qkv  = (const float*)d_in[1];
  const float* b_qkv  = (const float*)d_in[2];
  const float* w_proj = (const float*)d_in[3];
  const float* b_proj = (const float*)d_in[4];
  float* out = (float*)d_out;

  char* ws = (char*)d_ws;
  int* idx       = (int*)(ws + 0x200000);         // 1 KB
  u16* bt        = (u16*)(ws + 0x201000);         // 384 KB bf16 [768][256]
  u32* winflag   = (u32*)(ws + 0x270000);         // 1 KB (t,b,w): bit0 q, bit1 k, bit2 v
  float* region  = (float*)(ws + 0x271000);       // 64 KB [b][v][c]
  u32* qb        = (u32*)(ws + 0x300000);         // 2 MB each, natural token order
  u32* kb        = qb + (size_t)NT * NB * NW * NS * NH;
  u32* vb        = kb + (size_t)NT * NB * NW * NS * NH;
  u16* xw        = (u16*)(ws + 0x900000);         // 32 MB bf16 [65536][256]

  (void)hipMemsetAsync(ws + 0x270000, 0, 0x11000, stream);  // winflag + region
  k_prep<<<608, 256, 0, stream>>>(x, w_qkv, xw, bt, region);
  k_scores<<<NB * NW, 256, 0, stream>>>(region, idx);
  k_gemm<<<768, 512, 0, stream>>>(xw, bt, b_qkv, qb, kb, vb, winflag);
  k_attn<<<NT * NB * NW * 4, 256, 0, stream>>>(qb, kb, vb, idx, winflag, w_proj, b_proj, out);
}